// Round 2
// baseline (567.283 us; speedup 1.0000x reference)
//
#include <hip/hip_runtime.h>
#include <math.h>

// x: [B=2, C=1, D=64, H=256, W=256] fp32
// out: [B=2, 16, D=64, H=256, W=256] fp32
//   even channels = sobel magnitude of x (per 2D HxW slice, zero-padded SAME)
//   odd  channels = x
//
// One thread handles 4 consecutive W pixels; computes sobel once, then emits
// 16 float4 stores (8 sobel copies + 8 passthrough copies).
//
// v2b: all output stores are NONTEMPORAL (bypass L2 allocate — output is
// write-once/read-never, and polluting L2 evicts the 33.5 MB input that the
// 3x3 stencil re-reads ~4.5x). Passthrough stores are issued right after the
// center-row load so store issue overlaps the neighbor-row loads + sqrt chain.
// Uses a clang ext_vector_type for the stores: __builtin_nontemporal_store
// rejects HIP's float4 struct but accepts native float vectors.

#define SLICES 128   // B*D = 2*64
#define Hh 256
#define Ww 256
#define W4 64        // W/4
#define CH_STRIDE ((size_t)64 * Hh * Ww)   // one channel's D*H*W elements

typedef float f32x4 __attribute__((ext_vector_type(4)));

__global__ __launch_bounds__(256) void sobel_cat_kernel(
    const float* __restrict__ in, float* __restrict__ out) {
  const int tid = blockIdx.x * blockDim.x + threadIdx.x;
  // tid layout: [n: 0..127][h: 0..255][w4: 0..63]
  const int w4 = tid & (W4 - 1);
  const int h  = (tid >> 6) & (Hh - 1);
  const int n  = tid >> 14;            // b*64 + d
  const int b  = n >> 6;
  const int d  = n & 63;
  const int w  = w4 << 2;

  const float* slice = in + (size_t)n * (Hh * Ww);

  // rows: [w-1 .. w+4], zero-padded outside the image
  float rm[6], r0[6], rp[6];

  {
    // center row always valid — load FIRST so passthrough stores can issue
    // as soon as vmcnt drains past it.
    const float* rowp = slice + (size_t)h * Ww;
    f32x4 c = *(const f32x4*)(rowp + w);
    r0[1] = c.x; r0[2] = c.y; r0[3] = c.z; r0[4] = c.w;
    r0[0] = (w4 > 0)      ? rowp[w - 1] : 0.f;
    r0[5] = (w4 < W4 - 1) ? rowp[w + 4] : 0.f;
  }
  if (h > 0) {
    const float* rowp = slice + (size_t)(h - 1) * Ww;
    f32x4 c = *(const f32x4*)(rowp + w);
    rm[1] = c.x; rm[2] = c.y; rm[3] = c.z; rm[4] = c.w;
    rm[0] = (w4 > 0)      ? rowp[w - 1] : 0.f;
    rm[5] = (w4 < W4 - 1) ? rowp[w + 4] : 0.f;
  } else {
    #pragma unroll
    for (int i = 0; i < 6; ++i) rm[i] = 0.f;
  }
  if (h < Hh - 1) {
    const float* rowp = slice + (size_t)(h + 1) * Ww;
    f32x4 c = *(const f32x4*)(rowp + w);
    rp[1] = c.x; rp[2] = c.y; rp[3] = c.z; rp[4] = c.w;
    rp[0] = (w4 > 0)      ? rowp[w - 1] : 0.f;
    rp[5] = (w4 < W4 - 1) ? rowp[w + 4] : 0.f;
  } else {
    #pragma unroll
    for (int i = 0; i < 6; ++i) rp[i] = 0.f;
  }

  // out slice for (b, c, d): ((b*16 + c)*64 + d) = b*1024 + c*64 + d
  float* obase = out + ((size_t)(b * 1024 + d)) * (Hh * Ww) + (size_t)h * Ww + w;

  // Passthrough channels (odd c): value is just the center-row pixels.
  // Depends only on r0 — issue these 8 stores before the sobel math so the
  // write stream starts draining while sqrt computes.
  f32x4 v;
  v.x = r0[1]; v.y = r0[2]; v.z = r0[3]; v.w = r0[4];
  #pragma unroll
  for (int c = 1; c < 16; c += 2) {
    __builtin_nontemporal_store(v, (f32x4*)(obase + (size_t)c * CH_STRIDE));
  }

  float sv[4];
  #pragma unroll
  for (int i = 0; i < 4; ++i) {
    // pixel i sits at column w+i -> local index i+1; left=i, right=i+2
    float gx = (rm[i + 2] - rm[i]) + 2.f * (r0[i + 2] - r0[i]) + (rp[i + 2] - rp[i]);
    float gy = (rp[i] - rm[i]) + 2.f * (rp[i + 1] - rm[i + 1]) + (rp[i + 2] - rm[i + 2]);
    sv[i] = sqrtf(gx * gx + gy * gy);
  }
  f32x4 s;
  s.x = sv[0]; s.y = sv[1]; s.z = sv[2]; s.w = sv[3];

  #pragma unroll
  for (int c = 0; c < 16; c += 2) {
    __builtin_nontemporal_store(s, (f32x4*)(obase + (size_t)c * CH_STRIDE));
  }
}

extern "C" void kernel_launch(void* const* d_in, const int* in_sizes, int n_in,
                              void* d_out, int out_size, void* d_ws, size_t ws_size,
                              hipStream_t stream) {
  const float* x = (const float*)d_in[0];
  float* out = (float*)d_out;
  // total threads: 128 slices * 256 h * 64 w4 = 2,097,152
  const int total = SLICES * Hh * W4;
  const int block = 256;
  const int grid = total / block;  // 8192
  sobel_cat_kernel<<<grid, block, 0, stream>>>(x, out);
}

// Round 3
// 550.363 us; speedup vs baseline: 1.0307x; 1.0307x over previous
//
#include <hip/hip_runtime.h>
#include <math.h>

// x: [B=2, C=1, D=64, H=256, W=256] fp32
// out: [B=2, 16, D=64, H=256, W=256] fp32
//   even channels = sobel magnitude of x (per 2D HxW slice, zero-padded SAME)
//   odd  channels = x
//
// v3: each thread produces FOUR consecutive H rows (4 px wide), via a rolling
// 6-row input window:
//   - each channel's store stream gets 4 KB contiguous (4 row stores at
//     immediate offsets 0/1024/2048/3072) per wave visit -> DRAM row locality
//     comparable to a flat fill (which sustains 6.2 TB/s on this part).
//   - input read amplification drops 3x -> 1.5x.
//   - per-channel base address computed once; row stores use the 13-bit
//     immediate offset. Channel bases are uniform (out + c*CH_STRIDE) plus a
//     single 32-bit per-lane element offset (total output = 134M elems < 2^31).
//   - output stores remain nontemporal (write-once data; neutral in v2 but
//     correct to keep L2 for the re-read input rows).

#define SLICES 128   // B*D = 2*64
#define Hh 256
#define Ww 256
#define W4 64        // W/4
#define HQ 64        // H/4
#define CH_STRIDE ((size_t)64 * Hh * Ww)   // elements per output channel-slice

typedef float f32x4 __attribute__((ext_vector_type(4)));

__global__ __launch_bounds__(256) void sobel_cat_kernel(
    const float* __restrict__ in, float* __restrict__ out) {
  const int tid = blockIdx.x * blockDim.x + threadIdx.x;
  // tid layout: [n: 0..127][hq: 0..63][w4: 0..63]
  const int w4 = tid & (W4 - 1);
  const int hq = (tid >> 6) & (HQ - 1);
  const int n  = tid >> 12;            // b*64 + d
  const int b  = n >> 6;
  const int d  = n & 63;
  const int w  = w4 << 2;
  const int h0 = hq << 2;              // first of 4 output rows

  const float* slice = in + (size_t)n * (Hh * Ww);

  // rows[j] = input row (h0-1+j), j=0..5, columns [w-1 .. w+4], zero-padded.
  float rows[6][6];

  // j = 1..4 are always in-bounds (h0 in [0,252] -> rows h0..h0+3).
  #pragma unroll
  for (int j = 1; j < 5; ++j) {
    const float* rowp = slice + (size_t)(h0 - 1 + j) * Ww;
    f32x4 c = *(const f32x4*)(rowp + w);
    rows[j][1] = c.x; rows[j][2] = c.y; rows[j][3] = c.z; rows[j][4] = c.w;
    rows[j][0] = (w4 > 0)      ? rowp[w - 1] : 0.f;
    rows[j][5] = (w4 < W4 - 1) ? rowp[w + 4] : 0.f;
  }
  // j = 0: row h0-1, invalid only when hq == 0.
  if (h0 > 0) {
    const float* rowp = slice + (size_t)(h0 - 1) * Ww;
    f32x4 c = *(const f32x4*)(rowp + w);
    rows[0][1] = c.x; rows[0][2] = c.y; rows[0][3] = c.z; rows[0][4] = c.w;
    rows[0][0] = (w4 > 0)      ? rowp[w - 1] : 0.f;
    rows[0][5] = (w4 < W4 - 1) ? rowp[w + 4] : 0.f;
  } else {
    #pragma unroll
    for (int i = 0; i < 6; ++i) rows[0][i] = 0.f;
  }
  // j = 5: row h0+4, invalid only when hq == HQ-1.
  if (h0 < Hh - 4) {
    const float* rowp = slice + (size_t)(h0 + 4) * Ww;
    f32x4 c = *(const f32x4*)(rowp + w);
    rows[5][1] = c.x; rows[5][2] = c.y; rows[5][3] = c.z; rows[5][4] = c.w;
    rows[5][0] = (w4 > 0)      ? rowp[w - 1] : 0.f;
    rows[5][5] = (w4 < W4 - 1) ? rowp[w + 4] : 0.f;
  } else {
    #pragma unroll
    for (int i = 0; i < 6; ++i) rows[5][i] = 0.f;
  }

  // Sobel for the 4 output rows. All indices compile-time constant.
  f32x4 sv[4], vv[4];
  #pragma unroll
  for (int r = 0; r < 4; ++r) {
    float s[4];
    #pragma unroll
    for (int i = 0; i < 4; ++i) {
      float gx = (rows[r][i + 2] - rows[r][i])
               + 2.f * (rows[r + 1][i + 2] - rows[r + 1][i])
               + (rows[r + 2][i + 2] - rows[r + 2][i]);
      float gy = (rows[r + 2][i] - rows[r][i])
               + 2.f * (rows[r + 2][i + 1] - rows[r][i + 1])
               + (rows[r + 2][i + 2] - rows[r][i + 2]);
      s[i] = sqrtf(gx * gx + gy * gy);
    }
    sv[r].x = s[0]; sv[r].y = s[1]; sv[r].z = s[2]; sv[r].w = s[3];
    vv[r].x = rows[r + 1][1]; vv[r].y = rows[r + 1][2];
    vv[r].z = rows[r + 1][3]; vv[r].w = rows[r + 1][4];
  }

  // Per-lane element offset within a channel-slice block (fits 32 bits):
  // out[((b*16 + c)*64 + d)*65536 + h*256 + w]
  //   = out + c*CH_STRIDE + [(b*1024 + d)<<16 | h0<<8 | w] + r*256
  const unsigned base = ((unsigned)(b * 1024 + d) << 16)
                      + ((unsigned)h0 << 8) + (unsigned)w;
  #pragma unroll
  for (int c = 0; c < 16; ++c) {
    float* cp = out + (size_t)c * CH_STRIDE + base;   // uniform base + lane off
    #pragma unroll
    for (int r = 0; r < 4; ++r) {
      __builtin_nontemporal_store((c & 1) ? vv[r] : sv[r],
                                  (f32x4*)(cp + r * Ww));
    }
  }
}

extern "C" void kernel_launch(void* const* d_in, const int* in_sizes, int n_in,
                              void* d_out, int out_size, void* d_ws, size_t ws_size,
                              hipStream_t stream) {
  const float* x = (const float*)d_in[0];
  float* out = (float*)d_out;
  // total threads: 128 slices * 64 hq * 64 w4 = 524,288
  const int total = SLICES * HQ * W4;
  const int block = 256;
  const int grid = total / block;  // 2048
  sobel_cat_kernel<<<grid, block, 0, stream>>>(x, out);
}